// Round 2
// baseline (1844.388 us; speedup 1.0000x reference)
//
#include <hip/hip_runtime.h>

// Cost volume: out[b, dy*9+dx, h, w] = leaky( mean_c c1[b,c,h,w] * warped[b,c,h+dy-4,w+dx-4] )
// B=8 C=192 H=128 W=160, 81 offsets, fp32, zero-padded borders.
//
// R5 = R4 + channel-split (CSPLIT=2) for 2x thread-level parallelism.
// R4 was latency-bound at 31% occupancy: 720 blocks = 11 waves/CU (grid-
// starved; VGPR=64 would allow 32). Now each output unit is computed by TWO
// lanes of the same wave (lane l and l+32), each summing 96 of 192 channels.
// Grid: 1440 blocks -> ~22.5 waves/CU. Combine is a barrier-free wave-internal
// __shfl_xor(acc, 32) over the 72 accumulators; lanes 0-31 of each wave store.
//
// Per channel each lane loads its 16-float warped window (4 aligned dwordx4;
// 4*(w0-4) = 32g-16 is 16B aligned) + 8 c1 floats, does 72 FMAs with full
// in-register dx-reuse, prefetching the next channel under the current FMAs.
// No LDS, no syncthreads.
//
// Edges: W via clamped load column + 0/1 mask multiply for g==0/g==19;
// H via clamped row + zeroed epilogue (reference zero-pads, so an OOB warped
// row makes the whole (dy) output row exactly 0).

namespace {
constexpr int SR  = 4;
constexpr int MO  = 9;               // 2*SR+1
constexpr int NB  = 8;
constexpr int NC  = 192;
constexpr int CSPLIT = 2;
constexpr int CPL = NC / CSPLIT;     // 96 channels per lane
constexpr int NH  = 128;
constexpr int NW  = 160;
constexpr int HW  = NH * NW;
constexpr int WPT = 8;               // w pixels per unit
constexpr int NG  = NW / WPT;        // 20 w-groups
constexpr int UPH = MO * NG;         // 180 units per (b,h)
constexpr int NT  = 256;
constexpr int UNITS = NB * NH * UPH;          // 184320
constexpr int UPB   = NT / CSPLIT;            // 128 units per block
constexpr int NBLK  = UNITS / UPB;            // 1440 blocks (exact)
}

__global__ __launch_bounds__(NT, 6)
void costvol_kernel(const float* __restrict__ c1,
                    const float* __restrict__ warped,
                    const float* __restrict__ alphap,
                    float* __restrict__ out)
{
    const int tid   = threadIdx.x;
    const int lane  = tid & 63;
    const int wave  = tid >> 6;
    const int chalf = (lane >> 5) & 1;           // which 96-channel half
    const int uib   = (wave << 5) + (lane & 31); // unit index in block, 0..127
    const int u     = blockIdx.x * UPB + uib;

    const int g  = u % NG;
    const int dy = (u / NG) % MO;
    const int h  = (u / UPH) % NH;
    const int b  = u / (UPH * NH);

    const int w0 = g * WPT;
    const int hr = h + dy - SR;
    const bool vrow = (unsigned)hr < (unsigned)NH;
    const int hrc = vrow ? hr : (hr < 0 ? 0 : NH - 1);

    // four aligned 16B loads covering w0-4 .. w0+11; edge lanes clamp the
    // OOB load to a safe in-row column and zero it via mask.
    const int o0 = (g == 0)      ? 0  : (w0 - 4);
    const int o1 = w0;
    const int o2 = w0 + 4;
    const int o3 = (g == NG - 1) ? w0 : (w0 + 8);
    const float mA = (g == 0)      ? 0.0f : 1.0f;
    const float mB = (g == NG - 1) ? 0.0f : 1.0f;

    const size_t cbase = (size_t)b * NC * HW + (size_t)chalf * CPL * HW;
    const float* wp = warped + cbase + (size_t)hrc * NW;
    const float* cp = c1     + cbase + (size_t)h   * NW + w0;

    float acc[MO][WPT];
#pragma unroll
    for (int i = 0; i < MO; ++i)
#pragma unroll
        for (int j = 0; j < WPT; ++j) acc[i][j] = 0.0f;

    // prologue: channel 0 in flight
    float4 u0 = *(const float4*)(wp + o0);
    float4 u1 = *(const float4*)(wp + o1);
    float4 u2 = *(const float4*)(wp + o2);
    float4 u3 = *(const float4*)(wp + o3);
    float4 a0 = *(const float4*)(cp);
    float4 a1 = *(const float4*)(cp + 4);

#pragma unroll 2
    for (int c = 0; c < CPL; ++c) {
        const int cnx = (c + 1 < CPL) ? (c + 1) : c;  // last iter re-loads (harmless)
        const float* wn = wp + (size_t)cnx * HW;
        const float* cn = cp + (size_t)cnx * HW;
        // issue next channel's loads now; they fly under this channel's FMAs
        const float4 n0 = *(const float4*)(wn + o0);
        const float4 n1 = *(const float4*)(wn + o1);
        const float4 n2 = *(const float4*)(wn + o2);
        const float4 n3 = *(const float4*)(wn + o3);
        const float4 b0 = *(const float4*)(cn);
        const float4 b1 = *(const float4*)(cn + 4);

        const float win[16] = {
            u0.x * mA, u0.y * mA, u0.z * mA, u0.w * mA,
            u1.x, u1.y, u1.z, u1.w,
            u2.x, u2.y, u2.z, u2.w,
            u3.x * mB, u3.y * mB, u3.z * mB, u3.w * mB };
        const float cv[WPT] = { a0.x, a0.y, a0.z, a0.w,
                                a1.x, a1.y, a1.z, a1.w };

#pragma unroll
        for (int dx = 0; dx < MO; ++dx)
#pragma unroll
            for (int j = 0; j < WPT; ++j)
                acc[dx][j] = fmaf(cv[j], win[j + dx], acc[dx][j]);

        u0 = n0; u1 = n1; u2 = n2; u3 = n3; a0 = b0; a1 = b1;
    }

    // combine the two channel halves: wave-internal, no LDS, no barrier
#pragma unroll
    for (int dx = 0; dx < MO; ++dx)
#pragma unroll
        for (int j = 0; j < WPT; ++j)
            acc[dx][j] += __shfl_xor(acc[dx][j], 32);

    // epilogue (lower 32 lanes): mean + leaky relu; invalid row -> zeros
    if (chalf == 0) {
        const float scale = 1.0f / (float)NC;
        const float al = alphap[0];
        float* op = out + ((size_t)b * (MO * MO) + (size_t)(dy * MO)) * HW
                        + (size_t)h * NW + w0;
#pragma unroll
        for (int dx = 0; dx < MO; ++dx) {
            float r[WPT];
#pragma unroll
            for (int j = 0; j < WPT; ++j) {
                const float vv = vrow ? acc[dx][j] * scale : 0.0f;
                r[j] = (vv >= 0.0f) ? vv : al * vv;
            }
            float4* q = (float4*)(op + (size_t)dx * HW);
            q[0] = make_float4(r[0], r[1], r[2], r[3]);
            q[1] = make_float4(r[4], r[5], r[6], r[7]);
        }
    }
}

extern "C" void kernel_launch(void* const* d_in, const int* in_sizes, int n_in,
                              void* d_out, int out_size, void* d_ws, size_t ws_size,
                              hipStream_t stream) {
    (void)in_sizes; (void)n_in; (void)out_size; (void)d_ws; (void)ws_size;
    const float* c1     = (const float*)d_in[0];
    const float* warped = (const float*)d_in[1];
    const float* alpha  = (const float*)d_in[2];
    float* out          = (float*)d_out;
    costvol_kernel<<<dim3(NBLK), dim3(NT), 0, stream>>>(c1, warped, alpha, out);
}

// Round 3
// 448.665 us; speedup vs baseline: 4.1108x; 4.1108x over previous
//
#include <hip/hip_runtime.h>

// Cost volume: out[b, dy*9+dx, h, w] = leaky( mean_c c1[b,c,h,w] * warped[b,c,h+dy-4,w+dx-4] )
// B=8 C=192 H=128 W=160, 81 offsets, fp32, zero-padded borders.
//
// R6 = R4 structure (no LDS, no barriers, per-channel prefetch) with WPT 8->4.
// R5 post-mortem: __launch_bounds__(256,6) capped unified VGPR/AGPR at ~84;
// the 72-float accumulator spilled to scratch (VGPR 64->40, 6.9 GB of scratch
// HBM traffic, 1.68 ms). Occupancy must come from a SMALLER footprint, not a
// forced waves floor. WPT=4 halves acc (36 floats) + window (12) + prefetch
// (16) -> ~85 regs, safe under launch_bounds(256,4) cap of 128 (no spill),
// and doubles the grid to 1440 blocks (22.5 waves/CU offered vs R4's 11).
// Helps under both R4-limiter hypotheses (grid-starved OR reg-capped).
//
// Per channel each thread loads a 12-float warped window (3 aligned dwordx4;
// byte offset of w0-4 is 16g-16, 16B-aligned) + 4 c1 floats (1 dwordx4),
// does 36 FMAs with full in-register dx-reuse, prefetching the next channel
// under the current FMAs.
//
// Edges: W via clamped load column + 0/1 mask multiply for g==0/g==39;
// H via clamped row + zeroed epilogue (reference zero-pads, so an OOB warped
// row makes the whole (dy) output row exactly 0).

namespace {
constexpr int SR  = 4;
constexpr int MO  = 9;               // 2*SR+1
constexpr int NB  = 8;
constexpr int NC  = 192;
constexpr int NH  = 128;
constexpr int NW  = 160;
constexpr int HW  = NH * NW;
constexpr int WPT = 4;               // w pixels per thread
constexpr int NG  = NW / WPT;        // 40 w-groups
constexpr int UPH = MO * NG;         // 360 units per (b,h)
constexpr int NT  = 256;
constexpr int UNITS = NB * NH * UPH; // 368640
constexpr int NBLK  = UNITS / NT;    // 1440 blocks (exact)
}

__global__ __launch_bounds__(NT, 4)
void costvol_kernel(const float* __restrict__ c1,
                    const float* __restrict__ warped,
                    const float* __restrict__ alphap,
                    float* __restrict__ out)
{
    const int u  = blockIdx.x * NT + threadIdx.x;
    const int g  = u % NG;
    const int dy = (u / NG) % MO;
    const int h  = (u / UPH) % NH;
    const int b  = u / (UPH * NH);

    const int w0 = g * WPT;
    const int hr = h + dy - SR;
    const bool vrow = (unsigned)hr < (unsigned)NH;
    const int hrc = vrow ? hr : (hr < 0 ? 0 : NH - 1);

    // three aligned 16B loads covering w0-4 .. w0+7; edge lanes clamp the
    // OOB load to a safe in-row column and zero it via mask.
    const int o0 = (g == 0)      ? 0  : (w0 - 4);
    const int o1 = w0;
    const int o2 = (g == NG - 1) ? w0 : (w0 + 4);
    const float mA = (g == 0)      ? 0.0f : 1.0f;
    const float mB = (g == NG - 1) ? 0.0f : 1.0f;

    const size_t cbase = (size_t)b * NC * HW;
    const float* wp = warped + cbase + (size_t)hrc * NW;
    const float* cp = c1     + cbase + (size_t)h   * NW + w0;

    float acc[MO][WPT];
#pragma unroll
    for (int i = 0; i < MO; ++i)
#pragma unroll
        for (int j = 0; j < WPT; ++j) acc[i][j] = 0.0f;

    // prologue: channel 0 in flight
    float4 u0 = *(const float4*)(wp + o0);
    float4 u1 = *(const float4*)(wp + o1);
    float4 u2 = *(const float4*)(wp + o2);
    float4 a0 = *(const float4*)(cp);

#pragma unroll 2
    for (int c = 0; c < NC; ++c) {
        const int cnx = (c + 1 < NC) ? (c + 1) : c;   // last iter re-loads (harmless)
        const float* wn = wp + (size_t)cnx * HW;
        const float* cn = cp + (size_t)cnx * HW;
        // issue next channel's loads now; they fly under this channel's FMAs
        const float4 n0 = *(const float4*)(wn + o0);
        const float4 n1 = *(const float4*)(wn + o1);
        const float4 n2 = *(const float4*)(wn + o2);
        const float4 b0 = *(const float4*)(cn);

        const float win[12] = {
            u0.x * mA, u0.y * mA, u0.z * mA, u0.w * mA,
            u1.x, u1.y, u1.z, u1.w,
            u2.x * mB, u2.y * mB, u2.z * mB, u2.w * mB };
        const float cv[WPT] = { a0.x, a0.y, a0.z, a0.w };

#pragma unroll
        for (int dx = 0; dx < MO; ++dx)
#pragma unroll
            for (int j = 0; j < WPT; ++j)
                acc[dx][j] = fmaf(cv[j], win[j + dx], acc[dx][j]);

        u0 = n0; u1 = n1; u2 = n2; a0 = b0;
    }

    // epilogue: mean + leaky relu; invalid warped row -> exact zeros
    const float scale = 1.0f / (float)NC;
    const float al = alphap[0];
    float* op = out + ((size_t)b * (MO * MO) + (size_t)(dy * MO)) * HW
                    + (size_t)h * NW + w0;
#pragma unroll
    for (int dx = 0; dx < MO; ++dx) {
        float r[WPT];
#pragma unroll
        for (int j = 0; j < WPT; ++j) {
            const float vv = vrow ? acc[dx][j] * scale : 0.0f;
            r[j] = (vv >= 0.0f) ? vv : al * vv;
        }
        *(float4*)(op + (size_t)dx * HW) = make_float4(r[0], r[1], r[2], r[3]);
    }
}

extern "C" void kernel_launch(void* const* d_in, const int* in_sizes, int n_in,
                              void* d_out, int out_size, void* d_ws, size_t ws_size,
                              hipStream_t stream) {
    (void)in_sizes; (void)n_in; (void)out_size; (void)d_ws; (void)ws_size;
    const float* c1     = (const float*)d_in[0];
    const float* warped = (const float*)d_in[1];
    const float* alpha  = (const float*)d_in[2];
    float* out          = (float*)d_out;
    costvol_kernel<<<dim3(NBLK), dim3(NT), 0, stream>>>(c1, warped, alpha, out);
}

// Round 4
// 418.617 us; speedup vs baseline: 4.4059x; 1.0718x over previous
//
#include <hip/hip_runtime.h>

// Cost volume: out[b, dy*9+dx, h, w] = leaky( mean_c c1[b,c,h,w] * warped[b,c,h+dy-4,w+dx-4] )
// B=8 C=192 H=128 W=160, 81 offsets, fp32, zero-padded borders.
//
// R7 = R6 + (a) depth-2 software pipeline with 3 named register sets,
//           (b) XCD batch pinning (b = blockIdx & 7).
// R6 post-mortem: doubling grid TLP changed nothing (248->268us, VALUBusy
// ~24%) -> latency-bound per wave, not wave-starved. FETCH_SIZE 579MB vs
// 232MB unique input: 9x dy-reuse was being refetched because consecutive
// blocks round-robin across 8 XCD L2s and prefetch depth 1 exposes a full
// (in-order-return) HBM miss latency per channel. Fix: deepen the per-wave
// pipeline (issue->use distance = 2 compute blocks) and pin each batch to
// one XCD so row reuse hits the local L2 (1440 blocks = 8 batches x 180).
//
// Per channel each thread loads a 12-float warped window (3 aligned dwordx4;
// byte offset of w0-4 is 16g-16) + 4 c1 floats, does 36 FMAs with full
// in-register dx-reuse. The c-loop processes 3 channels per iteration with
// named sets A/B/C (no runtime-indexed arrays -> no scratch), issuing each
// set's loads ~2 compute-blocks before use. No LDS, no barriers.
//
// Edges: W via clamped load column + 0/1 mask multiply for g==0/g==39;
// H via clamped row + zeroed epilogue (reference zero-pads, so an OOB warped
// row makes the whole (dy) output row exactly 0).

namespace {
constexpr int SR  = 4;
constexpr int MO  = 9;               // 2*SR+1
constexpr int NB  = 8;
constexpr int NC  = 192;
constexpr int NH  = 128;
constexpr int NW  = 160;
constexpr int HW  = NH * NW;
constexpr int WPT = 4;               // w pixels per thread
constexpr int NG  = NW / WPT;        // 40 w-groups
constexpr int UPH = MO * NG;         // 360 units per (b,h)
constexpr int NT  = 256;
constexpr int UNITS = NB * NH * UPH; // 368640
constexpr int NBLK  = UNITS / NT;    // 1440 blocks = 8 batches x 180
}

__global__ __launch_bounds__(NT, 4)
void costvol_kernel(const float* __restrict__ c1,
                    const float* __restrict__ warped,
                    const float* __restrict__ alphap,
                    float* __restrict__ out)
{
    // XCD pinning: batch = blockIdx % 8 (one batch per XCD's L2),
    // unit-within-batch from blockIdx / 8.
    const int b  = blockIdx.x & (NB - 1);
    const int u  = (blockIdx.x >> 3) * NT + threadIdx.x;   // 0 .. 46079
    const int g  = u % NG;
    const int dy = (u / NG) % MO;
    const int h  = u / UPH;

    const int w0 = g * WPT;
    const int hr = h + dy - SR;
    const bool vrow = (unsigned)hr < (unsigned)NH;
    const int hrc = vrow ? hr : (hr < 0 ? 0 : NH - 1);

    // three aligned 16B loads covering w0-4 .. w0+7; edge lanes clamp the
    // OOB load to a safe in-row column and zero it via mask.
    const int o0 = (g == 0)      ? 0  : (w0 - 4);
    const int o1 = w0;
    const int o2 = (g == NG - 1) ? w0 : (w0 + 4);
    const float mA = (g == 0)      ? 0.0f : 1.0f;
    const float mB = (g == NG - 1) ? 0.0f : 1.0f;

    const size_t cbase = (size_t)b * NC * HW;
    const float* wp = warped + cbase + (size_t)hrc * NW;
    const float* cp = c1     + cbase + (size_t)h   * NW + w0;

    float acc[MO][WPT];
#pragma unroll
    for (int i = 0; i < MO; ++i)
#pragma unroll
        for (int j = 0; j < WPT; ++j) acc[i][j] = 0.0f;

    auto issue = [&](int idx, float4& W0, float4& W1, float4& W2, float4& C4) {
        const float* wq = wp + (size_t)idx * HW;
        const float* cq = cp + (size_t)idx * HW;
        W0 = *(const float4*)(wq + o0);
        W1 = *(const float4*)(wq + o1);
        W2 = *(const float4*)(wq + o2);
        C4 = *(const float4*)(cq);
    };
    auto compute = [&](const float4& W0, const float4& W1, const float4& W2,
                       const float4& C4) {
        const float win[12] = {
            W0.x * mA, W0.y * mA, W0.z * mA, W0.w * mA,
            W1.x, W1.y, W1.z, W1.w,
            W2.x * mB, W2.y * mB, W2.z * mB, W2.w * mB };
        const float cv[WPT] = { C4.x, C4.y, C4.z, C4.w };
#pragma unroll
        for (int dx = 0; dx < MO; ++dx)
#pragma unroll
            for (int j = 0; j < WPT; ++j)
                acc[dx][j] = fmaf(cv[j], win[j + dx], acc[dx][j]);
    };

    // named pipeline sets (no runtime-indexed arrays -> registers, not scratch)
    float4 aw0, aw1, aw2, ac4;
    float4 bw0, bw1, bw2, bc4;
    float4 cw0, cw1, cw2, cc4;

    // prologue: channels 0 and 1 in flight
    issue(0, aw0, aw1, aw2, ac4);
    issue(1, bw0, bw1, bw2, bc4);

    // steady state: 3 channels per iteration; each set issued ~2 compute
    // blocks before its use. Loop covers c = 0..188; issues up to 190.
#pragma unroll 1
    for (int c = 0; c < NC - 3; c += 3) {
        issue(c + 2, cw0, cw1, cw2, cc4);
        compute(aw0, aw1, aw2, ac4);
        issue(c + 3, aw0, aw1, aw2, ac4);
        compute(bw0, bw1, bw2, bc4);
        issue(c + 4, bw0, bw1, bw2, bc4);
        compute(cw0, cw1, cw2, cc4);
    }
    // tail (c = 189): A=189, B=190 already in flight; fetch 191 and drain.
    issue(NC - 1, cw0, cw1, cw2, cc4);
    compute(aw0, aw1, aw2, ac4);
    compute(bw0, bw1, bw2, bc4);
    compute(cw0, cw1, cw2, cc4);

    // epilogue: mean + leaky relu; invalid warped row -> exact zeros
    const float scale = 1.0f / (float)NC;
    const float al = alphap[0];
    float* op = out + ((size_t)b * (MO * MO) + (size_t)(dy * MO)) * HW
                    + (size_t)h * NW + w0;
#pragma unroll
    for (int dx = 0; dx < MO; ++dx) {
        float r[WPT];
#pragma unroll
        for (int j = 0; j < WPT; ++j) {
            const float vv = vrow ? acc[dx][j] * scale : 0.0f;
            r[j] = (vv >= 0.0f) ? vv : al * vv;
        }
        *(float4*)(op + (size_t)dx * HW) = make_float4(r[0], r[1], r[2], r[3]);
    }
}

extern "C" void kernel_launch(void* const* d_in, const int* in_sizes, int n_in,
                              void* d_out, int out_size, void* d_ws, size_t ws_size,
                              hipStream_t stream) {
    (void)in_sizes; (void)n_in; (void)out_size; (void)d_ws; (void)ws_size;
    const float* c1     = (const float*)d_in[0];
    const float* warped = (const float*)d_in[1];
    const float* alpha  = (const float*)d_in[2];
    float* out          = (float*)d_out;
    costvol_kernel<<<dim3(NBLK), dim3(NT), 0, stream>>>(c1, warped, alpha, out);
}

// Round 5
// 411.613 us; speedup vs baseline: 4.4809x; 1.0170x over previous
//
#include <hip/hip_runtime.h>

// Cost volume: out[b, dy*9+dx, h, w] = leaky( mean_c c1[b,c,h,w] * warped[b,c,h+dy-4,w+dx-4] )
// B=8 C=192 H=128 W=160, 81 offsets, fp32, zero-padded borders.
//
// R8 = R7 + (a) sched_barrier-pinned pipeline, (b) mask-free inner loop,
//           (c) saddr-form addressing.
// R7 post-mortem: VGPR=60 proves the compiler DEFLATED the 3-set pipeline
// (48 in-flight floats + 36 acc can't fit in 60 regs) -> loads were sunk to
// ~1 block before use; the intended latency cover never existed. Also 22% of
// the VALU stream was W-edge mask multiplies and ~25% was per-channel 64-bit
// address math. Fixes:
//  (a) __builtin_amdgcn_sched_barrier(0) after each issue block: loads cannot
//      sink below the fence -> issue-to-use distance of 2 compute blocks is
//      enforced in the emitted code. launch_bounds(256,4) caps VGPR at 128
//      (footprint ~100, no R5-style spill).
//  (b) no per-channel masking: W-edge garbage lands only in acc[dx][j] whose
//      window column is outside the image; those are zeroed once in the
//      epilogue (they must be exactly 0 = mean of zero-padded products).
//  (c) per-lane 32-bit offsets (hrc*NW+o) computed once; per-channel base is
//      a UNIFORM pointer (wB + ch*HW) -> scalar adds + global_load saddr form,
//      near-zero per-channel VALU address math.
// XCD pinning (b = blockIdx&7) kept: FETCH 579->128 MB in R7.

namespace {
constexpr int SR  = 4;
constexpr int MO  = 9;               // 2*SR+1
constexpr int NB  = 8;
constexpr int NC  = 192;
constexpr int NH  = 128;
constexpr int NW  = 160;
constexpr int HW  = NH * NW;
constexpr int WPT = 4;               // w pixels per thread
constexpr int NG  = NW / WPT;        // 40 w-groups
constexpr int UPH = MO * NG;         // 360 units per (b,h)
constexpr int NT  = 256;
constexpr int UNITS = NB * NH * UPH; // 368640
constexpr int NBLK  = UNITS / NT;    // 1440 blocks = 8 batches x 180
}

__global__ __launch_bounds__(NT, 4)
void costvol_kernel(const float* __restrict__ c1,
                    const float* __restrict__ warped,
                    const float* __restrict__ alphap,
                    float* __restrict__ out)
{
    // XCD pinning: batch = blockIdx % 8 (one batch per XCD's L2).
    const int b  = blockIdx.x & (NB - 1);
    const int u  = (blockIdx.x >> 3) * NT + threadIdx.x;   // 0 .. 46079
    const int g  = u % NG;
    const int dy = (u / NG) % MO;
    const int h  = u / UPH;

    const int w0 = g * WPT;
    const int hr = h + dy - SR;
    const bool vrow = (unsigned)hr < (unsigned)NH;
    const int hrc = vrow ? hr : (hr < 0 ? 0 : NH - 1);

    // three aligned 16B loads covering w0-4 .. w0+7; edge lanes clamp the
    // OOB load in-row (garbage is confined to known acc entries, zeroed at
    // the epilogue).
    const int o0 = (g == 0)      ? 0  : (w0 - 4);
    const int o1 = w0;
    const int o2 = (g == NG - 1) ? w0 : (w0 + 4);
    const bool e0 = (g == 0);
    const bool e1 = (g == NG - 1);

    // uniform bases (per block); per-lane 32-bit offsets computed once
    const float* wB = warped + (size_t)b * NC * HW;
    const float* cB = c1     + (size_t)b * NC * HW;
    const int rw = hrc * NW;
    const int woff0 = rw + o0;
    const int woff1 = rw + o1;
    const int woff2 = rw + o2;
    const int coff  = h * NW + w0;

    float acc[MO][WPT];
#pragma unroll
    for (int i = 0; i < MO; ++i)
#pragma unroll
        for (int j = 0; j < WPT; ++j) acc[i][j] = 0.0f;

    auto issue = [&](int ch, float4& W0, float4& W1, float4& W2, float4& C4) {
        const float* wq = wB + (size_t)ch * HW;   // uniform + per-lane offset
        const float* cq = cB + (size_t)ch * HW;
        W0 = *(const float4*)(wq + woff0);
        W1 = *(const float4*)(wq + woff1);
        W2 = *(const float4*)(wq + woff2);
        C4 = *(const float4*)(cq + coff);
    };
    auto compute = [&](const float4& W0, const float4& W1, const float4& W2,
                       const float4& C4) {
        const float win[12] = {
            W0.x, W0.y, W0.z, W0.w,
            W1.x, W1.y, W1.z, W1.w,
            W2.x, W2.y, W2.z, W2.w };
        const float cv[WPT] = { C4.x, C4.y, C4.z, C4.w };
#pragma unroll
        for (int dx = 0; dx < MO; ++dx)
#pragma unroll
            for (int j = 0; j < WPT; ++j)
                acc[dx][j] = fmaf(cv[j], win[j + dx], acc[dx][j]);
    };

    // named pipeline sets (no runtime-indexed arrays -> registers, not scratch)
    float4 aw0, aw1, aw2, ac4;
    float4 bw0, bw1, bw2, bc4;
    float4 cw0, cw1, cw2, cc4;

    // prologue: channels 0 and 1 in flight
    issue(0, aw0, aw1, aw2, ac4);
    issue(1, bw0, bw1, bw2, bc4);
    __builtin_amdgcn_sched_barrier(0);

    // steady state: 3 channels per iteration; sched_barrier(0) after each
    // issue block pins the loads above the following compute (the compiler
    // may not sink them to save registers as it did in R7).
#pragma unroll 1
    for (int c = 0; c < NC - 3; c += 3) {
        issue(c + 2, cw0, cw1, cw2, cc4);
        __builtin_amdgcn_sched_barrier(0);
        compute(aw0, aw1, aw2, ac4);
        issue(c + 3, aw0, aw1, aw2, ac4);
        __builtin_amdgcn_sched_barrier(0);
        compute(bw0, bw1, bw2, bc4);
        issue(c + 4, bw0, bw1, bw2, bc4);
        __builtin_amdgcn_sched_barrier(0);
        compute(cw0, cw1, cw2, cc4);
    }
    // tail (c = 189): A=189, B=190 already in flight; fetch 191 and drain.
    issue(NC - 1, cw0, cw1, cw2, cc4);
    __builtin_amdgcn_sched_barrier(0);
    compute(aw0, aw1, aw2, ac4);
    compute(bw0, bw1, bw2, bc4);
    compute(cw0, cw1, cw2, cc4);

    // epilogue: mean + leaky relu.
    //  - invalid warped row (vrow false) -> whole thread's outputs are 0
    //  - W-edge: acc[dx][j] whose window index s=j+dx refers to an
    //    out-of-image column (s<4 at g==0, s>=8 at g==NG-1) -> exactly 0
    const float scale = 1.0f / (float)NC;
    const float al = alphap[0];
    float* op = out + ((size_t)b * (MO * MO) + (size_t)(dy * MO)) * HW
                    + (size_t)h * NW + w0;
#pragma unroll
    for (int dx = 0; dx < MO; ++dx) {
        float r[WPT];
#pragma unroll
        for (int j = 0; j < WPT; ++j) {
            const int s = j + dx;
            float vv = acc[dx][j] * scale;
            const bool bad = (!vrow) || (e0 && (s < 4)) || (e1 && (s >= 8));
            vv = bad ? 0.0f : vv;
            r[j] = (vv >= 0.0f) ? vv : al * vv;
        }
        *(float4*)(op + (size_t)dx * HW) = make_float4(r[0], r[1], r[2], r[3]);
    }
}

extern "C" void kernel_launch(void* const* d_in, const int* in_sizes, int n_in,
                              void* d_out, int out_size, void* d_ws, size_t ws_size,
                              hipStream_t stream) {
    (void)in_sizes; (void)n_in; (void)out_size; (void)d_ws; (void)ws_size;
    const float* c1     = (const float*)d_in[0];
    const float* warped = (const float*)d_in[1];
    const float* alpha  = (const float*)d_in[2];
    float* out          = (float*)d_out;
    costvol_kernel<<<dim3(NBLK), dim3(NT), 0, stream>>>(c1, warped, alpha, out);
}